// Round 3
// baseline (486.066 us; speedup 1.0000x reference)
//
#include <hip/hip_runtime.h>
#include <math.h>
#include <stdint.h>

// NestedSwiGLUMLP on MI355X — round 2: split-bf16 MFMA path + audited fp32 fallback.
//
// Big-ws path (ws_size >= ~80.3MB):
//   k_zero/k_bin: expert binning (order-independent output => atomics OK)
//   k_wsplit  : pre-split w1,w2 into bf16 hi/lo arrays in ws (RNE; x = hi + lo, |lo| <= 2^-9|x|)
//   k_phaseA_mx: per expert e (DE=128<<e), tiles 64 tok x 64 gate cols (+ matching up cols),
//                3-pass split-bf16 MFMA (hi*hi + hi*lo + lo*hi), silu(gate)*up -> act (fp32, ws)
//   k_phaseB_mx: out = act @ w2[:, :DE]^T + b2 (same tile structure), zero-fill cols >= DE
// Fallback path: the audited fp32 baseline (phases write act into d_out; row-ownership safe).
//
// Error budget: dropped lo*lo term <= 2^-18 |x||w| per product; ~2e-6 abs at output. fp32-grade.
// MFMA work: 3 passes x 34.2 GFLOP ~ 101 GFLOP -> 49us @ 100% MfmaUtil (2075 TF measured 16x16).

#define NTOK 16384
#define DDIM 1024
#define HDIM 2048

typedef unsigned short u16;
typedef __attribute__((ext_vector_type(8))) short short8;   // 8 bf16 = 4 VGPRs (guide §3)
typedef __attribute__((ext_vector_type(4))) float f32x4;    // MFMA C/D frag

__device__ __forceinline__ u16 f2bf(float f) {              // RNE float->bf16 (bits)
    uint32_t u = __float_as_uint(f);
    return (u16)((u + 0x7fffu + ((u >> 16) & 1u)) >> 16);
}
__device__ __forceinline__ float bf2f(u16 h) {
    return __uint_as_float(((uint32_t)h) << 16);
}
// split 8 consecutive floats into hi/lo bf16 short8s, store 16B each
__device__ __forceinline__ void split8(const float* __restrict__ src,
                                       u16* __restrict__ dsth, u16* __restrict__ dstl) {
    float4 v0 = *(const float4*)(src);
    float4 v1 = *(const float4*)(src + 4);
    float t[8] = {v0.x, v0.y, v0.z, v0.w, v1.x, v1.y, v1.z, v1.w};
    short8 h8, l8;
#pragma unroll
    for (int i = 0; i < 8; ++i) {
        u16 h = f2bf(t[i]);
        u16 l = f2bf(t[i] - bf2f(h));
        h8[i] = (short)h;
        l8[i] = (short)l;
    }
    *(short8*)dsth = h8;
    *(short8*)dstl = l8;
}

__global__ __launch_bounds__(64) void k_zero(int* __restrict__ counts) {
    if (threadIdx.x < 4) counts[threadIdx.x] = 0;
}

__global__ __launch_bounds__(256) void k_bin(const int* __restrict__ mask,
                                             int* __restrict__ counts,
                                             int* __restrict__ bucket) {
    int i = blockIdx.x * 256 + threadIdx.x;
    int e = mask[i];
    int pos = atomicAdd(&counts[e], 1);
    bucket[e * NTOK + pos] = i;
}

// pre-split w1 (2048x1024) and w2 (1024x2048) into hi/lo bf16. 1024 blocks x 256 thr x 8 elems.
__global__ __launch_bounds__(256) void k_wsplit(const float* __restrict__ w1,
                                                const float* __restrict__ w2,
                                                u16* __restrict__ w1h, u16* __restrict__ w1l,
                                                u16* __restrict__ w2h, u16* __restrict__ w2l) {
    size_t o = ((size_t)blockIdx.x * 256 + threadIdx.x) * 8;   // < 2M
    split8(&w1[o], &w1h[o], &w1l[o]);
    split8(&w2[o], &w2h[o], &w2l[o]);
}

// ---------------- MFMA phase A: act = silu(x@w1g^T + b1g) * (x@w1u^T + b1u) --------------
// mfma_f32_16x16x32_bf16 layouts (guide §3, HW-verified m89/m91):
//   A: lane holds A[row=lane&15][k=(lane>>4)*8 + j], j=0..7  (one b128 from LDS)
//   B: lane holds B[k=(lane>>4)*8 + j][col=lane&15]  == W[col][k] for B=W^T -> same read pattern
//   C/D: elem r at (row=(lane>>4)*4 + r, col=lane&15)
template <int DE>
__device__ void phaseA_mx(const float* __restrict__ x,
                          const u16* __restrict__ w1h, const u16* __restrict__ w1l,
                          const float* __restrict__ b1,
                          const int* __restrict__ bucket, int cnt, int jt,
                          float* __restrict__ act,
                          int* toks, u16* Xh, u16* Xl,
                          u16* Wgh, u16* Wgl, u16* Wuh, u16* Wul) {
    static_assert(DE % 64 == 0, "");
    constexpr int KP = 40;  // padded LDS row stride (elems); 80B -> 2-way bank alias (free, m136)
    const int tid = threadIdx.x;
    const int lane = tid & 63;
    const int wid = tid >> 6;
    const int wr = wid >> 1, wc = wid & 1;     // wave grid 2 (token) x 2 (col)
    const int j0 = jt * 64;
    const int lr = lane & 15;
    const int lk = (lane >> 4) * 8;
    const int sr = tid >> 2, sc = (tid & 3) * 8;   // staging coords: row, col8

    for (int tile = blockIdx.x; tile * 64 < cnt; tile += gridDim.x) {
        const int base = tile * 64;
        __syncthreads();                        // protect toks/LDS from previous iteration
        if (tid < 64) {
            int p = base + tid;
            toks[tid] = bucket[p < cnt ? p : cnt - 1];
        }
        __syncthreads();

        const f32x4 zz = {0.f, 0.f, 0.f, 0.f};
        f32x4 gacc[2][2], uacc[2][2];
#pragma unroll
        for (int mi = 0; mi < 2; ++mi)
#pragma unroll
            for (int ni = 0; ni < 2; ++ni) { gacc[mi][ni] = zz; uacc[mi][ni] = zz; }

        for (int kc = 0; kc < DE; kc += 32) {
            // stage X (gather + split): 64 rows x 32 elems, one 8-chunk per thread
            split8(&x[(size_t)toks[sr] * DDIM + kc + sc], &Xh[sr * KP + sc], &Xl[sr * KP + sc]);
            // stage W1 gate+up (pre-split): 2 x 64 rows x 32 elems
#pragma unroll
            for (int g = 0; g < 2; ++g) {
                size_t row = (size_t)(g ? DE + j0 + sr : j0 + sr);
                short8 h = *(const short8*)&w1h[row * DDIM + kc + sc];
                short8 l = *(const short8*)&w1l[row * DDIM + kc + sc];
                *(short8*)&(g ? Wuh : Wgh)[sr * KP + sc] = h;
                *(short8*)&(g ? Wul : Wgl)[sr * KP + sc] = l;
            }
            __syncthreads();

            short8 Ah[2], Al[2];
#pragma unroll
            for (int mi = 0; mi < 2; ++mi) {
                int row = wr * 32 + mi * 16 + lr;
                Ah[mi] = *(const short8*)&Xh[row * KP + lk];
                Al[mi] = *(const short8*)&Xl[row * KP + lk];
            }
#pragma unroll
            for (int ni = 0; ni < 2; ++ni) {
                int rowb = wc * 32 + ni * 16 + lr;
                short8 bgh = *(const short8*)&Wgh[rowb * KP + lk];
                short8 bgl = *(const short8*)&Wgl[rowb * KP + lk];
                short8 buh = *(const short8*)&Wuh[rowb * KP + lk];
                short8 bul = *(const short8*)&Wul[rowb * KP + lk];
#pragma unroll
                for (int mi = 0; mi < 2; ++mi) {
                    gacc[mi][ni] = __builtin_amdgcn_mfma_f32_16x16x32_bf16(Ah[mi], bgh, gacc[mi][ni], 0, 0, 0);
                    gacc[mi][ni] = __builtin_amdgcn_mfma_f32_16x16x32_bf16(Ah[mi], bgl, gacc[mi][ni], 0, 0, 0);
                    gacc[mi][ni] = __builtin_amdgcn_mfma_f32_16x16x32_bf16(Al[mi], bgh, gacc[mi][ni], 0, 0, 0);
                    uacc[mi][ni] = __builtin_amdgcn_mfma_f32_16x16x32_bf16(Ah[mi], buh, uacc[mi][ni], 0, 0, 0);
                    uacc[mi][ni] = __builtin_amdgcn_mfma_f32_16x16x32_bf16(Ah[mi], bul, uacc[mi][ni], 0, 0, 0);
                    uacc[mi][ni] = __builtin_amdgcn_mfma_f32_16x16x32_bf16(Al[mi], buh, uacc[mi][ni], 0, 0, 0);
                }
            }
            __syncthreads();
        }

        // epilogue: silu(gate+bg)*(up+bu) -> act[tok][j0+col]
#pragma unroll
        for (int ni = 0; ni < 2; ++ni) {
            int gcol = j0 + wc * 32 + ni * 16 + lr;
            float bg = b1[gcol];
            float bu = b1[DE + gcol];
#pragma unroll
            for (int mi = 0; mi < 2; ++mi) {
#pragma unroll
                for (int r = 0; r < 4; ++r) {
                    int trow = wr * 32 + mi * 16 + (lane >> 4) * 4 + r;
                    if (base + trow < cnt) {
                        float g = gacc[mi][ni][r] + bg;
                        float u = uacc[mi][ni][r] + bu;
                        act[(size_t)toks[trow] * DDIM + gcol] = (g / (1.0f + expf(-g))) * u;
                    }
                }
            }
        }
    }
}

__global__ __launch_bounds__(256) void k_phaseA_mx(const float* __restrict__ x,
                                                   const u16* __restrict__ w1h,
                                                   const u16* __restrict__ w1l,
                                                   const float* __restrict__ b1,
                                                   const int* __restrict__ counts,
                                                   const int* __restrict__ bucket,
                                                   float* __restrict__ act) {
    __shared__ int toks[64];
    __shared__ __align__(16) u16 Xh[64 * 40], Xl[64 * 40];
    __shared__ __align__(16) u16 Wgh[64 * 40], Wgl[64 * 40], Wuh[64 * 40], Wul[64 * 40];
    int y = blockIdx.y;  // 30 = 2+4+8+16 j-tiles (DE/64 each)
    if (y < 2)
        phaseA_mx<128>(x, w1h, w1l, b1, bucket + 0 * NTOK, counts[0], y, act, toks, Xh, Xl, Wgh, Wgl, Wuh, Wul);
    else if (y < 6)
        phaseA_mx<256>(x, w1h, w1l, b1, bucket + 1 * NTOK, counts[1], y - 2, act, toks, Xh, Xl, Wgh, Wgl, Wuh, Wul);
    else if (y < 14)
        phaseA_mx<512>(x, w1h, w1l, b1, bucket + 2 * NTOK, counts[2], y - 6, act, toks, Xh, Xl, Wgh, Wgl, Wuh, Wul);
    else
        phaseA_mx<1024>(x, w1h, w1l, b1, bucket + 3 * NTOK, counts[3], y - 14, act, toks, Xh, Xl, Wgh, Wgl, Wuh, Wul);
}

// ---------------- MFMA phase B: out = act @ w2[:, :DE]^T + b2; zero cols >= DE -----------
template <int DE>
__device__ void phaseB_mx(const float* __restrict__ actsrc,
                          const u16* __restrict__ w2h, const u16* __restrict__ w2l,
                          const float* __restrict__ b2,
                          const int* __restrict__ bucket, int cnt, int it,
                          float* __restrict__ out,
                          int* toks, u16* Ah_, u16* Al_, u16* W2h_, u16* W2l_) {
    constexpr int KP = 40;
    const int tid = threadIdx.x;
    const int lane = tid & 63;
    const int wid = tid >> 6;
    const int wr = wid >> 1, wc = wid & 1;
    const int i0 = it * 64;
    const int lr = lane & 15;
    const int lk = (lane >> 4) * 8;
    const int sr = tid >> 2, sc = (tid & 3) * 8;

    for (int tile = blockIdx.x; tile * 64 < cnt; tile += gridDim.x) {
        const int base = tile * 64;
        __syncthreads();
        if (tid < 64) {
            int p = base + tid;
            toks[tid] = bucket[p < cnt ? p : cnt - 1];
        }
        __syncthreads();

        const f32x4 zz = {0.f, 0.f, 0.f, 0.f};
        f32x4 acc[2][2];
#pragma unroll
        for (int mi = 0; mi < 2; ++mi)
#pragma unroll
            for (int ni = 0; ni < 2; ++ni) acc[mi][ni] = zz;

        for (int kc = 0; kc < DE; kc += 32) {
            // stage act rows (gather + split) and w2 rows i0..i0+63 (pre-split)
            split8(&actsrc[(size_t)toks[sr] * DDIM + kc + sc], &Ah_[sr * KP + sc], &Al_[sr * KP + sc]);
            {
                size_t row = (size_t)(i0 + sr);
                short8 h = *(const short8*)&w2h[row * HDIM + kc + sc];
                short8 l = *(const short8*)&w2l[row * HDIM + kc + sc];
                *(short8*)&W2h_[sr * KP + sc] = h;
                *(short8*)&W2l_[sr * KP + sc] = l;
            }
            __syncthreads();

            short8 Af[2], Alo[2];
#pragma unroll
            for (int mi = 0; mi < 2; ++mi) {
                int row = wr * 32 + mi * 16 + lr;
                Af[mi] = *(const short8*)&Ah_[row * KP + lk];
                Alo[mi] = *(const short8*)&Al_[row * KP + lk];
            }
#pragma unroll
            for (int ni = 0; ni < 2; ++ni) {
                int rowb = wc * 32 + ni * 16 + lr;
                short8 bh = *(const short8*)&W2h_[rowb * KP + lk];
                short8 bl = *(const short8*)&W2l_[rowb * KP + lk];
#pragma unroll
                for (int mi = 0; mi < 2; ++mi) {
                    acc[mi][ni] = __builtin_amdgcn_mfma_f32_16x16x32_bf16(Af[mi], bh, acc[mi][ni], 0, 0, 0);
                    acc[mi][ni] = __builtin_amdgcn_mfma_f32_16x16x32_bf16(Af[mi], bl, acc[mi][ni], 0, 0, 0);
                    acc[mi][ni] = __builtin_amdgcn_mfma_f32_16x16x32_bf16(Alo[mi], bh, acc[mi][ni], 0, 0, 0);
                }
            }
            __syncthreads();
        }

#pragma unroll
        for (int ni = 0; ni < 2; ++ni) {
            int icol = i0 + wc * 32 + ni * 16 + lr;
            float bb = b2[icol];
#pragma unroll
            for (int mi = 0; mi < 2; ++mi) {
#pragma unroll
                for (int r = 0; r < 4; ++r) {
                    int trow = wr * 32 + mi * 16 + (lane >> 4) * 4 + r;
                    if (base + trow < cnt)
                        out[(size_t)toks[trow] * DDIM + icol] = acc[mi][ni][r] + bb;
                }
            }
        }

        // zero-fill cols [DE, DDIM) once per token tile (i-tile 0 blocks)
        if (it == 0 && DE < DDIM) {
            constexpr int TAIL4 = (DDIM - DE) / 4;
            const float4 z{0.f, 0.f, 0.f, 0.f};
            for (int idx = tid; idx < 64 * TAIL4; idx += 256) {
                int r = idx / TAIL4, c = idx % TAIL4;
                if (base + r < cnt)
                    *(float4*)&out[(size_t)toks[r] * DDIM + DE + c * 4] = z;
            }
        }
    }
}

__global__ __launch_bounds__(256) void k_phaseB_mx(const float* __restrict__ actsrc,
                                                   const u16* __restrict__ w2h,
                                                   const u16* __restrict__ w2l,
                                                   const float* __restrict__ b2,
                                                   const int* __restrict__ counts,
                                                   const int* __restrict__ bucket,
                                                   float* __restrict__ out) {
    __shared__ int toks[64];
    __shared__ __align__(16) u16 Ah_[64 * 40], Al_[64 * 40], W2h_[64 * 40], W2l_[64 * 40];
    int y = blockIdx.y;  // 30 = 2+4+8+16 i-tiles (DE/64 each)
    if (y < 2)
        phaseB_mx<128>(actsrc, w2h, w2l, b2, bucket + 0 * NTOK, counts[0], y, out, toks, Ah_, Al_, W2h_, W2l_);
    else if (y < 6)
        phaseB_mx<256>(actsrc, w2h, w2l, b2, bucket + 1 * NTOK, counts[1], y - 2, out, toks, Ah_, Al_, W2h_, W2l_);
    else if (y < 14)
        phaseB_mx<512>(actsrc, w2h, w2l, b2, bucket + 2 * NTOK, counts[2], y - 6, out, toks, Ah_, Al_, W2h_, W2l_);
    else
        phaseB_mx<1024>(actsrc, w2h, w2l, b2, bucket + 3 * NTOK, counts[3], y - 14, out, toks, Ah_, Al_, W2h_, W2l_);
}

// ======================= fp32 fallback (audited baseline, unchanged) =====================
template <int DE>
__device__ void phaseA_impl(const float* __restrict__ x, const float* __restrict__ w1,
                            const float* __restrict__ b1, const int* __restrict__ bucket,
                            int cnt, int jt, float* __restrict__ actout, int tileIdx,
                            int* toks, float* Xs, float* Wg, float* Wu) {
    constexpr int BT = 64, BJ = 64, KC = 32, KP = 36;
    const int tid = threadIdx.x;
    const int base = tileIdx * BT;
    if (base >= cnt) return;
    if (tid < BT) {
        int p = base + tid;
        toks[tid] = bucket[p < cnt ? p : cnt - 1];
    }
    __syncthreads();
    const int tg = tid & 15;
    const int cg = tid >> 4;
    const int j0 = jt * BJ;
    float ag[4][4] = {};
    float au[4][4] = {};
    for (int kc = 0; kc < DE; kc += KC) {
        for (int idx = tid; idx < BT * (KC / 4); idx += 256) {
            int r = idx >> 3, jf = idx & 7;
            *(float4*)&Xs[r * KP + jf * 4] = *(const float4*)&x[(size_t)toks[r] * DDIM + kc + jf * 4];
        }
        for (int idx = tid; idx < BJ * (KC / 4); idx += 256) {
            int r = idx >> 3, jf = idx & 7;
            *(float4*)&Wg[r * KP + jf * 4] = *(const float4*)&w1[(size_t)(j0 + r) * DDIM + kc + jf * 4];
            *(float4*)&Wu[r * KP + jf * 4] = *(const float4*)&w1[(size_t)(DE + j0 + r) * DDIM + kc + jf * 4];
        }
        __syncthreads();
#pragma unroll
        for (int k4 = 0; k4 < KC / 4; ++k4) {
            float4 xv[4];
#pragma unroll
            for (int tt = 0; tt < 4; ++tt) xv[tt] = *(const float4*)&Xs[(tg + 16 * tt) * KP + k4 * 4];
#pragma unroll
            for (int c = 0; c < 4; ++c) {
                float4 wg = *(const float4*)&Wg[(cg * 4 + c) * KP + k4 * 4];
                float4 wu = *(const float4*)&Wu[(cg * 4 + c) * KP + k4 * 4];
#pragma unroll
                for (int tt = 0; tt < 4; ++tt) {
                    float s = ag[tt][c];
                    s = fmaf(xv[tt].x, wg.x, s); s = fmaf(xv[tt].y, wg.y, s);
                    s = fmaf(xv[tt].z, wg.z, s); s = fmaf(xv[tt].w, wg.w, s);
                    ag[tt][c] = s;
                    float t2 = au[tt][c];
                    t2 = fmaf(xv[tt].x, wu.x, t2); t2 = fmaf(xv[tt].y, wu.y, t2);
                    t2 = fmaf(xv[tt].z, wu.z, t2); t2 = fmaf(xv[tt].w, wu.w, t2);
                    au[tt][c] = t2;
                }
            }
        }
        __syncthreads();
    }
    float4 bg = *(const float4*)&b1[j0 + cg * 4];
    float4 bu = *(const float4*)&b1[DE + j0 + cg * 4];
#pragma unroll
    for (int tt = 0; tt < 4; ++tt) {
        int tl = tg + 16 * tt;
        if (base + tl < cnt) {
            float g0 = ag[tt][0] + bg.x, g1 = ag[tt][1] + bg.y;
            float g2 = ag[tt][2] + bg.z, g3 = ag[tt][3] + bg.w;
            float u0 = au[tt][0] + bu.x, u1 = au[tt][1] + bu.y;
            float u2 = au[tt][2] + bu.z, u3 = au[tt][3] + bu.w;
            float4 o;
            o.x = (g0 / (1.0f + expf(-g0))) * u0;
            o.y = (g1 / (1.0f + expf(-g1))) * u1;
            o.z = (g2 / (1.0f + expf(-g2))) * u2;
            o.w = (g3 / (1.0f + expf(-g3))) * u3;
            *(float4*)&actout[(size_t)toks[tl] * DDIM + j0 + cg * 4] = o;
        }
    }
}

__global__ __launch_bounds__(256) void k_phaseA(const float* __restrict__ x,
                                                const float* __restrict__ w1,
                                                const float* __restrict__ b1,
                                                const int* __restrict__ counts,
                                                const int* __restrict__ bucket,
                                                float* __restrict__ out) {
    __shared__ int toks[64];
    __shared__ __align__(16) float Xs[64 * 36];
    __shared__ __align__(16) float Wg[64 * 36];
    __shared__ __align__(16) float Wu[64 * 36];
    int y = blockIdx.y;
    if (y < 2)
        phaseA_impl<128>(x, w1, b1, bucket + 0 * NTOK, counts[0], y, out, blockIdx.x, toks, Xs, Wg, Wu);
    else if (y < 6)
        phaseA_impl<256>(x, w1, b1, bucket + 1 * NTOK, counts[1], y - 2, out, blockIdx.x, toks, Xs, Wg, Wu);
    else if (y < 14)
        phaseA_impl<512>(x, w1, b1, bucket + 2 * NTOK, counts[2], y - 6, out, blockIdx.x, toks, Xs, Wg, Wu);
    else
        phaseA_impl<1024>(x, w1, b1, bucket + 3 * NTOK, counts[3], y - 14, out, blockIdx.x, toks, Xs, Wg, Wu);
}

template <int DE, int BT, int NI>
__device__ void phaseB_impl(const float* __restrict__ w2, const float* __restrict__ b2,
                            const int* __restrict__ bucket, int cnt, float* __restrict__ out,
                            int tileIdx, int* toks, float* As, float* Wt) {
    constexpr int KC = 16;
    constexpr int DEP = DE + 4;
    constexpr int NIP = NI + 4;
    constexpr int CT = 4;
    constexpr int CG = NI / CT;
    constexpr int TG = 256 / CG;
    static_assert(BT / TG == 4, "thread token tile must be 4");
    const int tid = threadIdx.x;
    const int base = tileIdx * BT;
    if (base >= cnt) return;
    if (tid < BT) {
        int p = base + tid;
        toks[tid] = bucket[p < cnt ? p : cnt - 1];
    }
    __syncthreads();
    for (int idx = tid; idx < BT * (DE / 4); idx += 256) {
        int r = idx / (DE / 4), jf = idx % (DE / 4);
        *(float4*)&As[r * DEP + jf * 4] = *(const float4*)&out[(size_t)toks[r] * DDIM + jf * 4];
    }
    __syncthreads();
    const int tg = tid % TG;
    const int cg = tid / TG;
    for (int i0 = 0; i0 < DE; i0 += NI) {
        float acc[4][4] = {};
        for (int jc = 0; jc < DE; jc += KC) {
            __syncthreads();
            for (int idx = tid; idx < NI * (KC / 4); idx += 256) {
                int i = idx >> 2, jf4 = idx & 3;
                float4 v = *(const float4*)&w2[(size_t)(i0 + i) * HDIM + jc + jf4 * 4];
                Wt[(jf4 * 4 + 0) * NIP + i] = v.x;
                Wt[(jf4 * 4 + 1) * NIP + i] = v.y;
                Wt[(jf4 * 4 + 2) * NIP + i] = v.z;
                Wt[(jf4 * 4 + 3) * NIP + i] = v.w;
            }
            __syncthreads();
#pragma unroll
            for (int j4 = 0; j4 < KC / 4; ++j4) {
                float xr[4][4];
#pragma unroll
                for (int tt = 0; tt < 4; ++tt) {
                    float4 v = *(const float4*)&As[(tg + TG * tt) * DEP + jc + j4 * 4];
                    xr[tt][0] = v.x; xr[tt][1] = v.y; xr[tt][2] = v.z; xr[tt][3] = v.w;
                }
#pragma unroll
                for (int jj = 0; jj < 4; ++jj) {
                    float4 wv = *(const float4*)&Wt[(j4 * 4 + jj) * NIP + cg * CT];
#pragma unroll
                    for (int tt = 0; tt < 4; ++tt) {
                        float xs = xr[tt][jj];
                        acc[tt][0] = fmaf(xs, wv.x, acc[tt][0]);
                        acc[tt][1] = fmaf(xs, wv.y, acc[tt][1]);
                        acc[tt][2] = fmaf(xs, wv.z, acc[tt][2]);
                        acc[tt][3] = fmaf(xs, wv.w, acc[tt][3]);
                    }
                }
            }
        }
        float4 bb = *(const float4*)&b2[i0 + cg * CT];
#pragma unroll
        for (int tt = 0; tt < 4; ++tt) {
            int tl = tg + TG * tt;
            if (base + tl < cnt) {
                float4 o;
                o.x = acc[tt][0] + bb.x;
                o.y = acc[tt][1] + bb.y;
                o.z = acc[tt][2] + bb.z;
                o.w = acc[tt][3] + bb.w;
                *(float4*)&out[(size_t)toks[tl] * DDIM + i0 + cg * CT] = o;
            }
        }
    }
    if (DE < DDIM) {
        constexpr int TAIL4 = (DDIM - DE) / 4;
        float4 z{0.f, 0.f, 0.f, 0.f};
        for (int idx = tid; idx < BT * TAIL4; idx += 256) {
            int r = idx / TAIL4, jf = idx % TAIL4;
            if (base + r < cnt)
                *(float4*)&out[(size_t)toks[r] * DDIM + DE + jf * 4] = z;
        }
    }
}

__global__ __launch_bounds__(256) void k_phaseB(const float* __restrict__ w2,
                                                const float* __restrict__ b2,
                                                const int* __restrict__ counts,
                                                const int* __restrict__ bucket,
                                                float* __restrict__ out) {
    __shared__ int toks[64];
    __shared__ __align__(16) float As[8448];
    __shared__ __align__(16) float Wt[8256];
    switch (blockIdx.y) {
        case 0: phaseB_impl<128, 64, 64>(w2, b2, bucket + 0 * NTOK, counts[0], out, blockIdx.x, toks, As, Wt); break;
        case 1: phaseB_impl<256, 32, 128>(w2, b2, bucket + 1 * NTOK, counts[1], out, blockIdx.x, toks, As, Wt); break;
        case 2: phaseB_impl<512, 16, 256>(w2, b2, bucket + 2 * NTOK, counts[2], out, blockIdx.x, toks, As, Wt); break;
        case 3: phaseB_impl<1024, 8, 512>(w2, b2, bucket + 3 * NTOK, counts[3], out, blockIdx.x, toks, As, Wt); break;
    }
}

// ==================================== launch =============================================
extern "C" void kernel_launch(void* const* d_in, const int* in_sizes, int n_in,
                              void* d_out, int out_size, void* d_ws, size_t ws_size,
                              hipStream_t stream) {
    const float* x  = (const float*)d_in[0];
    const float* w1 = (const float*)d_in[1];
    const float* b1 = (const float*)d_in[2];
    const float* w2 = (const float*)d_in[3];
    const float* b2 = (const float*)d_in[4];
    const int* mask = (const int*)d_in[5];
    float* out = (float*)d_out;

    // ws layout: counts @0 | bucket @256 (256KiB) | act @262400 (64MiB)
    //            | w1h | w1l | w2h | w2l (4MiB each)  => total 84,148,480 B
    char* wsb = (char*)d_ws;
    int* counts = (int*)wsb;
    int* bucket = (int*)(wsb + 256);
    float* act  = (float*)(wsb + 262400);
    u16* w1h = (u16*)(wsb + 67371264);
    u16* w1l = (u16*)(wsb + 71565568);
    u16* w2h = (u16*)(wsb + 75759872);
    u16* w2l = (u16*)(wsb + 79954176);
    const size_t NEED = 84148480ull;

    hipLaunchKernelGGL(k_zero, dim3(1), dim3(64), 0, stream, counts);
    hipLaunchKernelGGL(k_bin, dim3(NTOK / 256), dim3(256), 0, stream, mask, counts, bucket);

    if (ws_size >= NEED) {
        hipLaunchKernelGGL(k_wsplit, dim3(1024), dim3(256), 0, stream, w1, w2, w1h, w1l, w2h, w2l);
        hipLaunchKernelGGL(k_phaseA_mx, dim3(64, 30), dim3(256), 0, stream, x, w1h, w1l, b1, counts, bucket, act);
        hipLaunchKernelGGL(k_phaseB_mx, dim3(64, 30), dim3(256), 0, stream, act, w2h, w2l, b2, counts, bucket, out);
    } else {
        // fp32 fallback: act lives in d_out (row-ownership safe, audited)
        hipLaunchKernelGGL(k_phaseA, dim3(NTOK / 64, 30), dim3(256), 0, stream, x, w1, b1, counts, bucket, out);
        hipLaunchKernelGGL(k_phaseB, dim3(NTOK / 8, 4), dim3(256), 0, stream, w2, b2, counts, bucket, out);
    }
}

// Round 7
// 456.895 us; speedup vs baseline: 1.0638x; 1.0638x over previous
//
#include <hip/hip_runtime.h>
#include <math.h>
#include <stdint.h>

// NestedSwiGLUMLP on MI355X — round 5/6: split-bf16 MFMA + global_load_lds 2-phase dbuf.
//
// Pipeline (big-ws path):
//   k_zero/k_bin : expert binning
//   k_wsplit     : w1,w2 -> bf16 hi/lo in ws (once per call)
//   k_xsplit     : x -> bf16 hi/lo stored in d_out (dead until phaseB overwrites it)
//   k_phaseA_v3  : act(bf16 hi/lo in ws) = silu(x@w1g^T+b1g)*(x@w1u^T+b1u), 3-pass split MFMA
//   k_phaseB_v3  : out = act@w2[:,:DE]^T + b2 (3-pass), zero-fill cols >= DE
// GEMM loops: 64tok x 64col tiles, KC=32, double-buffered LDS filled by
// global_load_lds (16B), issue-next-then-compute-current, one __syncthreads
// per K-step (its vmcnt(0)+lgkmcnt(0) drain sits AFTER compute = overlap).
// LDS layout: [64 rows][4 chunks of 16B] linear (gload_lds needs linear dest);
// bank conflicts killed by XOR swizzle on BOTH sides (rule 21):
//   phys_chunk = logical_chunk ^ ((row>>1)&3)  -> banks fully spread on ds_read_b128.
// Accuracy: hi*hi + hi*lo + lo*hi (drop lo*lo <= 2^-18) — round 3 passed absmax 2e-3.

#define NTOK 16384
#define DDIM 1024
#define HDIM 2048

typedef unsigned short u16;
typedef __attribute__((ext_vector_type(8))) short short8;
typedef __attribute__((ext_vector_type(4))) float f32x4;

__device__ __forceinline__ u16 f2bf(float f) {
    uint32_t u = __float_as_uint(f);
    return (u16)((u + 0x7fffu + ((u >> 16) & 1u)) >> 16);
}
__device__ __forceinline__ float bf2f(u16 h) {
    return __uint_as_float(((uint32_t)h) << 16);
}
__device__ __forceinline__ void split8(const float* __restrict__ src,
                                       u16* __restrict__ dsth, u16* __restrict__ dstl) {
    float4 v0 = *(const float4*)(src);
    float4 v1 = *(const float4*)(src + 4);
    float t[8] = {v0.x, v0.y, v0.z, v0.w, v1.x, v1.y, v1.z, v1.w};
    short8 h8, l8;
#pragma unroll
    for (int i = 0; i < 8; ++i) {
        u16 h = f2bf(t[i]);
        u16 l = f2bf(t[i] - bf2f(h));
        h8[i] = (short)h;
        l8[i] = (short)l;
    }
    *(short8*)dsth = h8;
    *(short8*)dstl = l8;
}

// async 16B global -> LDS. LDS dest must be wave-uniform (HW adds lane*16);
// addrspacecast (not integer truncation) for both pointers.
__device__ __forceinline__ void gload16(const void* g, void* l) {
    __builtin_amdgcn_global_load_lds(
        (const __attribute__((address_space(1))) void*)g,
        (__attribute__((address_space(3))) void*)l,
        16, 0, 0);
}

__global__ __launch_bounds__(64) void k_zero(int* __restrict__ counts) {
    if (threadIdx.x < 4) counts[threadIdx.x] = 0;
}

__global__ __launch_bounds__(256) void k_bin(const int* __restrict__ mask,
                                             int* __restrict__ counts,
                                             int* __restrict__ bucket) {
    int i = blockIdx.x * 256 + threadIdx.x;
    int e = mask[i];
    int pos = atomicAdd(&counts[e], 1);
    bucket[e * NTOK + pos] = i;
}

__global__ __launch_bounds__(256) void k_wsplit(const float* __restrict__ w1,
                                                const float* __restrict__ w2,
                                                u16* __restrict__ w1h, u16* __restrict__ w1l,
                                                u16* __restrict__ w2h, u16* __restrict__ w2l) {
    size_t o = ((size_t)blockIdx.x * 256 + threadIdx.x) * 8;   // < 2M
    split8(&w1[o], &w1h[o], &w1l[o]);
    split8(&w2[o], &w2h[o], &w2l[o]);
}

__global__ __launch_bounds__(256) void k_xsplit(const float* __restrict__ x,
                                                u16* __restrict__ xh, u16* __restrict__ xl) {
    size_t o = ((size_t)blockIdx.x * 256 + threadIdx.x) * 8;   // < 16M
    split8(&x[o], &xh[o], &xl[o]);
}

// ---------------- phase A: act = silu(x@w1g^T + b1g) * (x@w1u^T + b1u) ----------------
// LDS per buffer: 6 arrays (Xh,Xl,Wgh,Wgl,Wuh,Wul) x [64 rows][32 u16] linear.
// u16-unit strides: array 2048, part(16 rows) 512, row 32. Buffer stride 12288 u16.
template <int DE>
__device__ void phaseA_v3(const u16* __restrict__ xh, const u16* __restrict__ xl,
                          const u16* __restrict__ w1h, const u16* __restrict__ w1l,
                          const float* __restrict__ b1,
                          const int* __restrict__ bucket, int cnt, int jt,
                          u16* __restrict__ acth, u16* __restrict__ actl,
                          int* toks, u16* lds) {
    const int tid = threadIdx.x;
    const int lane = tid & 63;
    const int wid = tid >> 6;
    const int wr = wid >> 1, wc = wid & 1;     // wave grid 2(token) x 2(col)
    const int j0 = jt * 64;
    const int lr = lane & 15;
    const int lgrp = lane >> 4;                // logical 16B chunk for frag reads
    const int nk = DE / 32;

    for (int tile = blockIdx.x; tile * 64 < cnt; tile += gridDim.x) {
        const int base = tile * 64;
        __syncthreads();                       // prev tile fully done (toks reads complete)
        if (tid < 64) {
            int p = base + tid;
            toks[tid] = bucket[p < cnt ? p : cnt - 1];
        }
        __syncthreads();                       // toks visible

        // per-thread stage descriptors: 24 chunks = (array a, part p); wave w owns q=0..5
        const u16* src[6];
        int dstoff[6];                         // u16 offset within one buffer (wave-uniform)
        {
            const int r16 = lane >> 2, pc = lane & 3;
#pragma unroll
            for (int q = 0; q < 6; ++q) {
                int idx = wid * 6 + q;
                int a = idx >> 2, p = idx & 3;
                int r = p * 16 + r16;
                int ko = (pc ^ ((r >> 1) & 3)) * 8;   // inverse-swizzled source chunk
                const u16* s;
                if (a == 0)      s = &xh[(size_t)toks[r] * DDIM + ko];
                else if (a == 1) s = &xl[(size_t)toks[r] * DDIM + ko];
                else if (a == 2) s = &w1h[(size_t)(j0 + r) * DDIM + ko];
                else if (a == 3) s = &w1l[(size_t)(j0 + r) * DDIM + ko];
                else if (a == 4) s = &w1h[(size_t)(DE + j0 + r) * DDIM + ko];
                else             s = &w1l[(size_t)(DE + j0 + r) * DDIM + ko];
                src[q] = s;
                dstoff[q] = a * 2048 + p * 512;
            }
        }

        f32x4 gacc[2][2], uacc[2][2];
        const f32x4 zz = {0.f, 0.f, 0.f, 0.f};
#pragma unroll
        for (int mi = 0; mi < 2; ++mi)
#pragma unroll
            for (int ni = 0; ni < 2; ++ni) { gacc[mi][ni] = zz; uacc[mi][ni] = zz; }

        // prologue: fill buffer 0
#pragma unroll
        for (int q = 0; q < 6; ++q) gload16(src[q], lds + dstoff[q]);
        __syncthreads();                       // vmcnt(0) drain: buf0 ready

        for (int kt = 0; kt < nk; ++kt) {
            const int cur = kt & 1;
            if (kt + 1 < nk) {                 // issue next K-step loads FIRST
                const int boff = (cur ^ 1) * 12288;
                const int kc = (kt + 1) * 32;
#pragma unroll
                for (int q = 0; q < 6; ++q) gload16(src[q] + kc, lds + boff + dstoff[q]);
            }
            const u16* B = lds + cur * 12288;
            short8 Ah[2], Al[2];
#pragma unroll
            for (int mi = 0; mi < 2; ++mi) {
                int row = wr * 32 + mi * 16 + lr;
                int pb = (lgrp ^ ((row >> 1) & 3)) * 8;
                Ah[mi] = *(const short8*)&B[0 * 2048 + row * 32 + pb];
                Al[mi] = *(const short8*)&B[1 * 2048 + row * 32 + pb];
            }
#pragma unroll
            for (int ni = 0; ni < 2; ++ni) {
                int rowb = wc * 32 + ni * 16 + lr;
                int pb = (lgrp ^ ((rowb >> 1) & 3)) * 8;
                short8 bgh = *(const short8*)&B[2 * 2048 + rowb * 32 + pb];
                short8 bgl = *(const short8*)&B[3 * 2048 + rowb * 32 + pb];
                short8 buh = *(const short8*)&B[4 * 2048 + rowb * 32 + pb];
                short8 bul = *(const short8*)&B[5 * 2048 + rowb * 32 + pb];
#pragma unroll
                for (int mi = 0; mi < 2; ++mi) {
                    gacc[mi][ni] = __builtin_amdgcn_mfma_f32_16x16x32_bf16(Ah[mi], bgh, gacc[mi][ni], 0, 0, 0);
                    gacc[mi][ni] = __builtin_amdgcn_mfma_f32_16x16x32_bf16(Ah[mi], bgl, gacc[mi][ni], 0, 0, 0);
                    gacc[mi][ni] = __builtin_amdgcn_mfma_f32_16x16x32_bf16(Al[mi], bgh, gacc[mi][ni], 0, 0, 0);
                    uacc[mi][ni] = __builtin_amdgcn_mfma_f32_16x16x32_bf16(Ah[mi], buh, uacc[mi][ni], 0, 0, 0);
                    uacc[mi][ni] = __builtin_amdgcn_mfma_f32_16x16x32_bf16(Ah[mi], bul, uacc[mi][ni], 0, 0, 0);
                    uacc[mi][ni] = __builtin_amdgcn_mfma_f32_16x16x32_bf16(Al[mi], buh, uacc[mi][ni], 0, 0, 0);
                }
            }
            __syncthreads();   // vmcnt(0): next buf ready; lgkmcnt(0): my reads done
        }

        // epilogue: act = silu(gate+bg)*(up+bu), split to bf16 hi/lo
#pragma unroll
        for (int ni = 0; ni < 2; ++ni) {
            int gcol = j0 + wc * 32 + ni * 16 + lr;
            float bg = b1[gcol];
            float bu = b1[DE + gcol];
#pragma unroll
            for (int mi = 0; mi < 2; ++mi) {
#pragma unroll
                for (int r = 0; r < 4; ++r) {
                    int trow = wr * 32 + mi * 16 + lgrp * 4 + r;
                    if (base + trow < cnt) {
                        float g = gacc[mi][ni][r] + bg;
                        float u = uacc[mi][ni][r] + bu;
                        float a = (g / (1.0f + expf(-g))) * u;
                        size_t off = (size_t)toks[trow] * DDIM + gcol;
                        u16 h = f2bf(a);
                        acth[off] = h;
                        actl[off] = f2bf(a - bf2f(h));
                    }
                }
            }
        }
    }
}

__global__ __launch_bounds__(256) void k_phaseA_v3(const u16* __restrict__ xh,
                                                   const u16* __restrict__ xl,
                                                   const u16* __restrict__ w1h,
                                                   const u16* __restrict__ w1l,
                                                   const float* __restrict__ b1,
                                                   const int* __restrict__ counts,
                                                   const int* __restrict__ bucket,
                                                   u16* __restrict__ acth,
                                                   u16* __restrict__ actl) {
    __shared__ int toks[64];
    __shared__ __align__(16) u16 lds[2 * 6 * 2048];   // 48 KiB
    int y = blockIdx.y;  // 30 = 2+4+8+16 j-tiles
    if (y < 2)
        phaseA_v3<128>(xh, xl, w1h, w1l, b1, bucket + 0 * NTOK, counts[0], y, acth, actl, toks, lds);
    else if (y < 6)
        phaseA_v3<256>(xh, xl, w1h, w1l, b1, bucket + 1 * NTOK, counts[1], y - 2, acth, actl, toks, lds);
    else if (y < 14)
        phaseA_v3<512>(xh, xl, w1h, w1l, b1, bucket + 2 * NTOK, counts[2], y - 6, acth, actl, toks, lds);
    else
        phaseA_v3<1024>(xh, xl, w1h, w1l, b1, bucket + 3 * NTOK, counts[3], y - 14, acth, actl, toks, lds);
}

// ---------------- phase B: out = act @ w2[:, :DE]^T + b2; zero cols >= DE ----------------
template <int DE>
__device__ void phaseB_v3(const u16* __restrict__ acth, const u16* __restrict__ actl,
                          const u16* __restrict__ w2h, const u16* __restrict__ w2l,
                          const float* __restrict__ b2,
                          const int* __restrict__ bucket, int cnt, int it,
                          float* __restrict__ out,
                          int* toks, u16* lds) {
    const int tid = threadIdx.x;
    const int lane = tid & 63;
    const int wid = tid >> 6;
    const int wr = wid >> 1, wc = wid & 1;
    const int i0 = it * 64;
    const int lr = lane & 15;
    const int lgrp = lane >> 4;
    const int nk = DE / 32;

    for (int tile = blockIdx.x; tile * 64 < cnt; tile += gridDim.x) {
        const int base = tile * 64;
        __syncthreads();
        if (tid < 64) {
            int p = base + tid;
            toks[tid] = bucket[p < cnt ? p : cnt - 1];
        }
        __syncthreads();

        const u16* src[4];
        int dstoff[4];
        {
            const int r16 = lane >> 2, pc = lane & 3;
#pragma unroll
            for (int q = 0; q < 4; ++q) {
                int idx = wid * 4 + q;
                int a = idx >> 2, p = idx & 3;
                int r = p * 16 + r16;
                int ko = (pc ^ ((r >> 1) & 3)) * 8;
                const u16* s;
                if (a == 0)      s = &acth[(size_t)toks[r] * DDIM + ko];
                else if (a == 1) s = &actl[(size_t)toks[r] * DDIM + ko];
                else if (a == 2) s = &w2h[(size_t)(i0 + r) * HDIM + ko];
                else             s = &w2l[(size_t)(i0 + r) * HDIM + ko];
                src[q] = s;
                dstoff[q] = a * 2048 + p * 512;
            }
        }

        f32x4 acc[2][2];
        const f32x4 zz = {0.f, 0.f, 0.f, 0.f};
#pragma unroll
        for (int mi = 0; mi < 2; ++mi)
#pragma unroll
            for (int ni = 0; ni < 2; ++ni) acc[mi][ni] = zz;

#pragma unroll
        for (int q = 0; q < 4; ++q) gload16(src[q], lds + dstoff[q]);
        __syncthreads();

        for (int kt = 0; kt < nk; ++kt) {
            const int cur = kt & 1;
            if (kt + 1 < nk) {
                const int boff = (cur ^ 1) * 8192;
                const int kc = (kt + 1) * 32;
#pragma unroll
                for (int q = 0; q < 4; ++q) gload16(src[q] + kc, lds + boff + dstoff[q]);
            }
            const u16* B = lds + cur * 8192;
            short8 Ah[2], Al[2];
#pragma unroll
            for (int mi = 0; mi < 2; ++mi) {
                int row = wr * 32 + mi * 16 + lr;
                int pb = (lgrp ^ ((row >> 1) & 3)) * 8;
                Ah[mi] = *(const short8*)&B[0 * 2048 + row * 32 + pb];
                Al[mi] = *(const short8*)&B[1 * 2048 + row * 32 + pb];
            }
#pragma unroll
            for (int ni = 0; ni < 2; ++ni) {
                int rowb = wc * 32 + ni * 16 + lr;
                int pb = (lgrp ^ ((rowb >> 1) & 3)) * 8;
                short8 bh = *(const short8*)&B[2 * 2048 + rowb * 32 + pb];
                short8 bl = *(const short8*)&B[3 * 2048 + rowb * 32 + pb];
#pragma unroll
                for (int mi = 0; mi < 2; ++mi) {
                    acc[mi][ni] = __builtin_amdgcn_mfma_f32_16x16x32_bf16(Ah[mi], bh, acc[mi][ni], 0, 0, 0);
                    acc[mi][ni] = __builtin_amdgcn_mfma_f32_16x16x32_bf16(Ah[mi], bl, acc[mi][ni], 0, 0, 0);
                    acc[mi][ni] = __builtin_amdgcn_mfma_f32_16x16x32_bf16(Al[mi], bh, acc[mi][ni], 0, 0, 0);
                }
            }
            __syncthreads();
        }

#pragma unroll
        for (int ni = 0; ni < 2; ++ni) {
            int icol = i0 + wc * 32 + ni * 16 + lr;
            float bb = b2[icol];
#pragma unroll
            for (int mi = 0; mi < 2; ++mi) {
#pragma unroll
                for (int r = 0; r < 4; ++r) {
                    int trow = wr * 32 + mi * 16 + lgrp * 4 + r;
                    if (base + trow < cnt)
                        out[(size_t)toks[trow] * DDIM + icol] = acc[mi][ni][r] + bb;
                }
            }
        }

        if (it == 0 && DE < DDIM) {            // zero-fill cols [DE, DDIM)
            constexpr int TAIL4 = (DDIM - DE) / 4;
            const float4 z{0.f, 0.f, 0.f, 0.f};
            for (int idx = tid; idx < 64 * TAIL4; idx += 256) {
                int r = idx / TAIL4, c = idx % TAIL4;
                if (base + r < cnt)
                    *(float4*)&out[(size_t)toks[r] * DDIM + DE + c * 4] = z;
            }
        }
    }
}

__global__ __launch_bounds__(256) void k_phaseB_v3(const u16* __restrict__ acth,
                                                   const u16* __restrict__ actl,
                                                   const u16* __restrict__ w2h,
                                                   const u16* __restrict__ w2l,
                                                   const float* __restrict__ b2,
                                                   const int* __restrict__ counts,
                                                   const int* __restrict__ bucket,
                                                   float* __restrict__ out) {
    __shared__ int toks[64];
    __shared__ __align__(16) u16 lds[2 * 4 * 2048];   // 32 KiB
    int y = blockIdx.y;  // 30 = 2+4+8+16 i-tiles
    if (y < 2)
        phaseB_v3<128>(acth, actl, w2h, w2l, b2, bucket + 0 * NTOK, counts[0], y, out, toks, lds);
    else if (y < 6)
        phaseB_v3<256>(acth, actl, w2h, w2l, b2, bucket + 1 * NTOK, counts[1], y - 2, out, toks, lds);
    else if (y < 14)
        phaseB_v3<512>(acth, actl, w2h, w2l, b2, bucket + 2 * NTOK, counts[2], y - 6, out, toks, lds);
    else
        phaseB_v3<1024>(acth, actl, w2h, w2l, b2, bucket + 3 * NTOK, counts[3], y - 14, out, toks, lds);
}

// ======================= fp32 fallback (audited baseline, unchanged) =====================
template <int DE>
__device__ void phaseA_impl(const float* __restrict__ x, const float* __restrict__ w1,
                            const float* __restrict__ b1, const int* __restrict__ bucket,
                            int cnt, int jt, float* __restrict__ actout, int tileIdx,
                            int* toks, float* Xs, float* Wg, float* Wu) {
    constexpr int BT = 64, BJ = 64, KC = 32, KP = 36;
    const int tid = threadIdx.x;
    const int base = tileIdx * BT;
    if (base >= cnt) return;
    if (tid < BT) {
        int p = base + tid;
        toks[tid] = bucket[p < cnt ? p : cnt - 1];
    }
    __syncthreads();
    const int tg = tid & 15;
    const int cg = tid >> 4;
    const int j0 = jt * BJ;
    float ag[4][4] = {};
    float au[4][4] = {};
    for (int kc = 0; kc < DE; kc += KC) {
        for (int idx = tid; idx < BT * (KC / 4); idx += 256) {
            int r = idx >> 3, jf = idx & 7;
            *(float4*)&Xs[r * KP + jf * 4] = *(const float4*)&x[(size_t)toks[r] * DDIM + kc + jf * 4];
        }
        for (int idx = tid; idx < BJ * (KC / 4); idx += 256) {
            int r = idx >> 3, jf = idx & 7;
            *(float4*)&Wg[r * KP + jf * 4] = *(const float4*)&w1[(size_t)(j0 + r) * DDIM + kc + jf * 4];
            *(float4*)&Wu[r * KP + jf * 4] = *(const float4*)&w1[(size_t)(DE + j0 + r) * DDIM + kc + jf * 4];
        }
        __syncthreads();
#pragma unroll
        for (int k4 = 0; k4 < KC / 4; ++k4) {
            float4 xv[4];
#pragma unroll
            for (int tt = 0; tt < 4; ++tt) xv[tt] = *(const float4*)&Xs[(tg + 16 * tt) * KP + k4 * 4];
#pragma unroll
            for (int c = 0; c < 4; ++c) {
                float4 wg = *(const float4*)&Wg[(cg * 4 + c) * KP + k4 * 4];
                float4 wu = *(const float4*)&Wu[(cg * 4 + c) * KP + k4 * 4];
#pragma unroll
                for (int tt = 0; tt < 4; ++tt) {
                    float s = ag[tt][c];
                    s = fmaf(xv[tt].x, wg.x, s); s = fmaf(xv[tt].y, wg.y, s);
                    s = fmaf(xv[tt].z, wg.z, s); s = fmaf(xv[tt].w, wg.w, s);
                    ag[tt][c] = s;
                    float t2 = au[tt][c];
                    t2 = fmaf(xv[tt].x, wu.x, t2); t2 = fmaf(xv[tt].y, wu.y, t2);
                    t2 = fmaf(xv[tt].z, wu.z, t2); t2 = fmaf(xv[tt].w, wu.w, t2);
                    au[tt][c] = t2;
                }
            }
        }
        __syncthreads();
    }
    float4 bg = *(const float4*)&b1[j0 + cg * 4];
    float4 bu = *(const float4*)&b1[DE + j0 + cg * 4];
#pragma unroll
    for (int tt = 0; tt < 4; ++tt) {
        int tl = tg + 16 * tt;
        if (base + tl < cnt) {
            float g0 = ag[tt][0] + bg.x, g1 = ag[tt][1] + bg.y;
            float g2 = ag[tt][2] + bg.z, g3 = ag[tt][3] + bg.w;
            float u0 = au[tt][0] + bu.x, u1 = au[tt][1] + bu.y;
            float u2 = au[tt][2] + bu.z, u3 = au[tt][3] + bu.w;
            float4 o;
            o.x = (g0 / (1.0f + expf(-g0))) * u0;
            o.y = (g1 / (1.0f + expf(-g1))) * u1;
            o.z = (g2 / (1.0f + expf(-g2))) * u2;
            o.w = (g3 / (1.0f + expf(-g3))) * u3;
            *(float4*)&actout[(size_t)toks[tl] * DDIM + j0 + cg * 4] = o;
        }
    }
}

__global__ __launch_bounds__(256) void k_phaseA(const float* __restrict__ x,
                                                const float* __restrict__ w1,
                                                const float* __restrict__ b1,
                                                const int* __restrict__ counts,
                                                const int* __restrict__ bucket,
                                                float* __restrict__ out) {
    __shared__ int toks[64];
    __shared__ __align__(16) float Xs[64 * 36];
    __shared__ __align__(16) float Wg[64 * 36];
    __shared__ __align__(16) float Wu[64 * 36];
    int y = blockIdx.y;
    if (y < 2)
        phaseA_impl<128>(x, w1, b1, bucket + 0 * NTOK, counts[0], y, out, blockIdx.x, toks, Xs, Wg, Wu);
    else if (y < 6)
        phaseA_impl<256>(x, w1, b1, bucket + 1 * NTOK, counts[1], y - 2, out, blockIdx.x, toks, Xs, Wg, Wu);
    else if (y < 14)
        phaseA_impl<512>(x, w1, b1, bucket + 2 * NTOK, counts[2], y - 6, out, blockIdx.x, toks, Xs, Wg, Wu);
    else
        phaseA_impl<1024>(x, w1, b1, bucket + 3 * NTOK, counts[3], y - 14, out, blockIdx.x, toks, Xs, Wg, Wu);
}

template <int DE, int BT, int NI>
__device__ void phaseB_impl(const float* __restrict__ w2, const float* __restrict__ b2,
                            const int* __restrict__ bucket, int cnt, float* __restrict__ out,
                            int tileIdx, int* toks, float* As, float* Wt) {
    constexpr int KC = 16;
    constexpr int DEP = DE + 4;
    constexpr int NIP = NI + 4;
    constexpr int CT = 4;
    constexpr int CG = NI / CT;
    constexpr int TG = 256 / CG;
    static_assert(BT / TG == 4, "thread token tile must be 4");
    const int tid = threadIdx.x;
    const int base = tileIdx * BT;
    if (base >= cnt) return;
    if (tid < BT) {
        int p = base + tid;
        toks[tid] = bucket[p < cnt ? p : cnt - 1];
    }
    __syncthreads();
    for (int idx = tid; idx < BT * (DE / 4); idx += 256) {
        int r = idx / (DE / 4), jf = idx % (DE / 4);
        *(float4*)&As[r * DEP + jf * 4] = *(const float4*)&out[(size_t)toks[r] * DDIM + jf * 4];
    }
    __syncthreads();
    const int tg = tid % TG;
    const int cg = tid / TG;
    for (int i0 = 0; i0 < DE; i0 += NI) {
        float acc[4][4] = {};
        for (int jc = 0; jc < DE; jc += KC) {
            __syncthreads();
            for (int idx = tid; idx < NI * (KC / 4); idx += 256) {
                int i = idx >> 2, jf4 = idx & 3;
                float4 v = *(const float4*)&w2[(size_t)(i0 + i) * HDIM + jc + jf4 * 4];
                Wt[(jf4 * 4 + 0) * NIP + i] = v.x;
                Wt[(jf4 * 4 + 1) * NIP + i] = v.y;
                Wt[(jf4 * 4 + 2) * NIP + i] = v.z;
                Wt[(jf4 * 4 + 3) * NIP + i] = v.w;
            }
            __syncthreads();
#pragma unroll
            for (int j4 = 0; j4 < KC / 4; ++j4) {
                float xr[4][4];
#pragma unroll
                for (int tt = 0; tt < 4; ++tt) {
                    float4 v = *(const float4*)&As[(tg + TG * tt) * DEP + jc + j4 * 4];
                    xr[tt][0] = v.x; xr[tt][1] = v.y; xr[tt][2] = v.z; xr[tt][3] = v.w;
                }
#pragma unroll
                for (int jj = 0; jj < 4; ++jj) {
                    float4 wv = *(const float4*)&Wt[(j4 * 4 + jj) * NIP + cg * CT];
#pragma unroll
                    for (int tt = 0; tt < 4; ++tt) {
                        float xs = xr[tt][jj];
                        acc[tt][0] = fmaf(xs, wv.x, acc[tt][0]);
                        acc[tt][1] = fmaf(xs, wv.y, acc[tt][1]);
                        acc[tt][2] = fmaf(xs, wv.z, acc[tt][2]);
                        acc[tt][3] = fmaf(xs, wv.w, acc[tt][3]);
                    }
                }
            }
        }
        float4 bb = *(const float4*)&b2[i0 + cg * CT];
#pragma unroll
        for (int tt = 0; tt < 4; ++tt) {
            int tl = tg + TG * tt;
            if (base + tl < cnt) {
                float4 o;
                o.x = acc[tt][0] + bb.x;
                o.y = acc[tt][1] + bb.y;
                o.z = acc[tt][2] + bb.z;
                o.w = acc[tt][3] + bb.w;
                *(float4*)&out[(size_t)toks[tl] * DDIM + i0 + cg * CT] = o;
            }
        }
    }
    if (DE < DDIM) {
        constexpr int TAIL4 = (DDIM - DE) / 4;
        float4 z{0.f, 0.f, 0.f, 0.f};
        for (int idx = tid; idx < BT * TAIL4; idx += 256) {
            int r = idx / TAIL4, jf = idx % TAIL4;
            if (base + r < cnt)
                *(float4*)&out[(size_t)toks[r] * DDIM + DE + jf * 4] = z;
        }
    }
}

__global__ __launch_bounds__(256) void k_phaseB(const float* __restrict__ w2,
                                                const float* __restrict__ b2,
                                                const int* __restrict__ counts,
                                                const int* __restrict__ bucket,
                                                float* __restrict__ out) {
    __shared__ int toks[64];
    __shared__ __align__(16) float As[8448];
    __shared__ __align__(16) float Wt[8256];
    switch (blockIdx.y) {
        case 0: phaseB_impl<128, 64, 64>(w2, b2, bucket + 0 * NTOK, counts[0], out, blockIdx.x, toks, As, Wt); break;
        case 1: phaseB_impl<256, 32, 128>(w2, b2, bucket + 1 * NTOK, counts[1], out, blockIdx.x, toks, As, Wt); break;
        case 2: phaseB_impl<512, 16, 256>(w2, b2, bucket + 2 * NTOK, counts[2], out, blockIdx.x, toks, As, Wt); break;
        case 3: phaseB_impl<1024, 8, 512>(w2, b2, bucket + 3 * NTOK, counts[3], out, blockIdx.x, toks, As, Wt); break;
    }
}

// ==================================== launch =============================================
extern "C" void kernel_launch(void* const* d_in, const int* in_sizes, int n_in,
                              void* d_out, int out_size, void* d_ws, size_t ws_size,
                              hipStream_t stream) {
    const float* x  = (const float*)d_in[0];
    const float* w1 = (const float*)d_in[1];
    const float* b1 = (const float*)d_in[2];
    const float* w2 = (const float*)d_in[3];
    const float* b2 = (const float*)d_in[4];
    const int* mask = (const int*)d_in[5];
    float* out = (float*)d_out;

    // ws: counts@0 | bucket@256 (256KiB) | acth@262400 (32MiB) | actl (32MiB)
    //     | w1h | w1l | w2h | w2l (4MiB each) => 84,148,480 B (same NEED as round 3, proven OK)
    char* wsb = (char*)d_ws;
    int* counts = (int*)wsb;
    int* bucket = (int*)(wsb + 256);
    u16* acth = (u16*)(wsb + 262400);
    u16* actl = (u16*)(wsb + 33816832);
    u16* w1h = (u16*)(wsb + 67371264);
    u16* w1l = (u16*)(wsb + 71565568);
    u16* w2h = (u16*)(wsb + 75759872);
    u16* w2l = (u16*)(wsb + 79954176);
    const size_t NEED = 84148480ull;

    hipLaunchKernelGGL(k_zero, dim3(1), dim3(64), 0, stream, counts);
    hipLaunchKernelGGL(k_bin, dim3(NTOK / 256), dim3(256), 0, stream, mask, counts, bucket);

    if (ws_size >= NEED) {
        // x hi/lo lives in d_out (dead until phaseB overwrites it with the real output)
        u16* xh = (u16*)d_out;
        u16* xl = xh + (size_t)NTOK * DDIM;
        hipLaunchKernelGGL(k_wsplit, dim3(1024), dim3(256), 0, stream, w1, w2, w1h, w1l, w2h, w2l);
        hipLaunchKernelGGL(k_xsplit, dim3(8192), dim3(256), 0, stream, x, xh, xl);
        hipLaunchKernelGGL(k_phaseA_v3, dim3(64, 30), dim3(256), 0, stream,
                           xh, xl, w1h, w1l, b1, counts, bucket, acth, actl);
        hipLaunchKernelGGL(k_phaseB_v3, dim3(64, 30), dim3(256), 0, stream,
                           acth, actl, w2h, w2l, b2, counts, bucket, out);
    } else {
        hipLaunchKernelGGL(k_phaseA, dim3(NTOK / 64, 30), dim3(256), 0, stream, x, w1, b1, counts, bucket, out);
        hipLaunchKernelGGL(k_phaseB, dim3(NTOK / 8, 4), dim3(256), 0, stream, w2, b2, counts, bucket, out);
    }
}

// Round 9
// 384.193 us; speedup vs baseline: 1.2652x; 1.1892x over previous
//
#include <hip/hip_runtime.h>
#include <math.h>
#include <stdint.h>

// NestedSwiGLUMLP on MI355X — round 8/9: 3-buffer counted-vmcnt pipeline + LDS-binned k_bin.
//
// r7 post-mortem: latency-bound (MfmaUtil 17.7, VALUBusy 19, Occ 14, HBM 8%, conflicts 0).
// The 2-buffer __syncthreads loop serializes on load latency every K-step (vmcnt(0) drain).
// Fix: 3 LDS buffers, issue stage(k+2) then s_waitcnt vmcnt(2Q) (count = 2 newer stages
// in flight, T4 formula), raw s_barrier + sched_barrier(0) fences (rule 18), second
// barrier after MFMA protects the oldest buffer from WAR. Never vmcnt(0) mid-loop.
// Also: k_bin had 16384 same-address global atomics (~4096-way contention) -> LDS
// aggregation, 4 global atomics per block.
//
// Accuracy unchanged: 3-pass split-bf16 (hi*hi + hi*lo + lo*hi); passed twice absmax 2e-3.

#define NTOK 16384
#define DDIM 1024
#define HDIM 2048

typedef unsigned short u16;
typedef __attribute__((ext_vector_type(8))) short short8;
typedef __attribute__((ext_vector_type(4))) float f32x4;

__device__ __forceinline__ u16 f2bf(float f) {
    uint32_t u = __float_as_uint(f);
    return (u16)((u + 0x7fffu + ((u >> 16) & 1u)) >> 16);
}
__device__ __forceinline__ float bf2f(u16 h) {
    return __uint_as_float(((uint32_t)h) << 16);
}
__device__ __forceinline__ void split8(const float* __restrict__ src,
                                       u16* __restrict__ dsth, u16* __restrict__ dstl) {
    float4 v0 = *(const float4*)(src);
    float4 v1 = *(const float4*)(src + 4);
    float t[8] = {v0.x, v0.y, v0.z, v0.w, v1.x, v1.y, v1.z, v1.w};
    short8 h8, l8;
#pragma unroll
    for (int i = 0; i < 8; ++i) {
        u16 h = f2bf(t[i]);
        u16 l = f2bf(t[i] - bf2f(h));
        h8[i] = (short)h;
        l8[i] = (short)l;
    }
    *(short8*)dsth = h8;
    *(short8*)dstl = l8;
}

// async 16B global -> LDS (LDS dest wave-uniform; HW adds lane*16)
__device__ __forceinline__ void gload16(const void* g, void* l) {
    __builtin_amdgcn_global_load_lds(
        (const __attribute__((address_space(1))) void*)g,
        (__attribute__((address_space(3))) void*)l,
        16, 0, 0);
}

__global__ __launch_bounds__(64) void k_zero(int* __restrict__ counts) {
    if (threadIdx.x < 4) counts[threadIdx.x] = 0;
}

// LDS-aggregated binning: per-block LDS atomics (fast), 4 global atomics per block.
// Bucket order is arbitrary -> output order-independent, race-free.
__global__ __launch_bounds__(256) void k_bin(const int* __restrict__ mask,
                                             int* __restrict__ counts,
                                             int* __restrict__ bucket) {
    __shared__ int lcnt[4], lbase[4];
    const int tid = threadIdx.x;
    const int i = blockIdx.x * 256 + tid;
    if (tid < 4) lcnt[tid] = 0;
    __syncthreads();
    const int e = mask[i];
    const int rank = atomicAdd(&lcnt[e], 1);       // LDS atomic
    __syncthreads();
    if (tid < 4) lbase[tid] = atomicAdd(&counts[tid], lcnt[tid]);  // global, 4/block
    __syncthreads();
    bucket[e * NTOK + lbase[e] + rank] = i;
}

__global__ __launch_bounds__(256) void k_wsplit(const float* __restrict__ w1,
                                                const float* __restrict__ w2,
                                                u16* __restrict__ w1h, u16* __restrict__ w1l,
                                                u16* __restrict__ w2h, u16* __restrict__ w2l) {
    size_t o = ((size_t)blockIdx.x * 256 + threadIdx.x) * 8;
    split8(&w1[o], &w1h[o], &w1l[o]);
    split8(&w2[o], &w2h[o], &w2l[o]);
}

__global__ __launch_bounds__(256) void k_xsplit(const float* __restrict__ x,
                                                u16* __restrict__ xh, u16* __restrict__ xl) {
    size_t o = ((size_t)blockIdx.x * 256 + threadIdx.x) * 8;
    split8(&x[o], &xh[o], &xl[o]);
}

// ---------------- phase A: act = silu(x@w1g^T + b1g) * (x@w1u^T + b1u) ----------------
// 3 LDS buffers x 6 arrays x [64 rows][32 u16]; buffer stride 12288 u16 (24.5 KB).
// Per step: issue stage(k+2) -> vmcnt(12) -> s_barrier -> ds_read+MFMA -> s_barrier.
template <int DE>
__device__ void phaseA_v3(const u16* __restrict__ xh, const u16* __restrict__ xl,
                          const u16* __restrict__ w1h, const u16* __restrict__ w1l,
                          const float* __restrict__ b1,
                          const int* __restrict__ bucket, int cnt, int jt,
                          u16* __restrict__ acth, u16* __restrict__ actl,
                          int* toks, u16* lds) {
    const int tid = threadIdx.x;
    const int lane = tid & 63;
    const int wid = tid >> 6;
    const int wr = wid >> 1, wc = wid & 1;     // wave grid 2(token) x 2(col)
    const int j0 = jt * 64;
    const int lr = lane & 15;
    const int lgrp = lane >> 4;
    const int nk = DE / 32;                    // 4..32 (always >= 4)
    constexpr int BUF = 12288;                 // u16 per buffer

    for (int tile = blockIdx.x; tile * 64 < cnt; tile += gridDim.x) {
        const int base = tile * 64;
        __syncthreads();                       // full drain: prev epilogue stores + LDS reuse
        if (tid < 64) {
            int p = base + tid;
            toks[tid] = bucket[p < cnt ? p : cnt - 1];
        }
        __syncthreads();

        const u16* src[6];
        int dstoff[6];                         // wave-uniform within-buffer offsets
        {
            const int r16 = lane >> 2, pc = lane & 3;
#pragma unroll
            for (int q = 0; q < 6; ++q) {
                int idx = wid * 6 + q;
                int a = idx >> 2, p = idx & 3;
                int r = p * 16 + r16;
                int ko = (pc ^ ((r >> 1) & 3)) * 8;   // inverse-swizzled source chunk
                const u16* s;
                if (a == 0)      s = &xh[(size_t)toks[r] * DDIM + ko];
                else if (a == 1) s = &xl[(size_t)toks[r] * DDIM + ko];
                else if (a == 2) s = &w1h[(size_t)(j0 + r) * DDIM + ko];
                else if (a == 3) s = &w1l[(size_t)(j0 + r) * DDIM + ko];
                else if (a == 4) s = &w1h[(size_t)(DE + j0 + r) * DDIM + ko];
                else             s = &w1l[(size_t)(DE + j0 + r) * DDIM + ko];
                src[q] = s;
                dstoff[q] = a * 2048 + p * 512;
            }
        }

        f32x4 gacc[2][2], uacc[2][2];
        const f32x4 zz = {0.f, 0.f, 0.f, 0.f};
#pragma unroll
        for (int mi = 0; mi < 2; ++mi)
#pragma unroll
            for (int ni = 0; ni < 2; ++ni) { gacc[mi][ni] = zz; uacc[mi][ni] = zz; }

        // prologue: stage buffers 0 and 1 (12 outstanding loads per wave)
#pragma unroll
        for (int q = 0; q < 6; ++q) gload16(src[q], lds + dstoff[q]);
#pragma unroll
        for (int q = 0; q < 6; ++q) gload16(src[q] + 32, lds + BUF + dstoff[q]);

        int coff = 0;            // current buffer
        int soff = 2 * BUF;      // stage target for kt+2
        for (int kt = 0; kt < nk; ++kt) {
            if (kt + 2 < nk) {
                const int kc = (kt + 2) * 32;
#pragma unroll
                for (int q = 0; q < 6; ++q) gload16(src[q] + kc, lds + soff + dstoff[q]);
                asm volatile("s_waitcnt vmcnt(12)" ::: "memory");  // stage(kt) done
            } else if (kt + 1 < nk) {
                asm volatile("s_waitcnt vmcnt(6)" ::: "memory");
            } else {
                asm volatile("s_waitcnt vmcnt(0)" ::: "memory");
            }
            __builtin_amdgcn_s_barrier();              // all waves staged buf kt
            __builtin_amdgcn_sched_barrier(0);         // no hoisting above (rule 18)

            const u16* B = lds + coff;
            short8 Ah[2], Al[2];
#pragma unroll
            for (int mi = 0; mi < 2; ++mi) {
                int row = wr * 32 + mi * 16 + lr;
                int pb = (lgrp ^ ((row >> 1) & 3)) * 8;
                Ah[mi] = *(const short8*)&B[0 * 2048 + row * 32 + pb];
                Al[mi] = *(const short8*)&B[1 * 2048 + row * 32 + pb];
            }
#pragma unroll
            for (int ni = 0; ni < 2; ++ni) {
                int rowb = wc * 32 + ni * 16 + lr;
                int pb = (lgrp ^ ((rowb >> 1) & 3)) * 8;
                short8 bgh = *(const short8*)&B[2 * 2048 + rowb * 32 + pb];
                short8 bgl = *(const short8*)&B[3 * 2048 + rowb * 32 + pb];
                short8 buh = *(const short8*)&B[4 * 2048 + rowb * 32 + pb];
                short8 bul = *(const short8*)&B[5 * 2048 + rowb * 32 + pb];
#pragma unroll
                for (int mi = 0; mi < 2; ++mi) {
                    gacc[mi][ni] = __builtin_amdgcn_mfma_f32_16x16x32_bf16(Ah[mi], bgh, gacc[mi][ni], 0, 0, 0);
                    gacc[mi][ni] = __builtin_amdgcn_mfma_f32_16x16x32_bf16(Ah[mi], bgl, gacc[mi][ni], 0, 0, 0);
                    gacc[mi][ni] = __builtin_amdgcn_mfma_f32_16x16x32_bf16(Al[mi], bgh, gacc[mi][ni], 0, 0, 0);
                    uacc[mi][ni] = __builtin_amdgcn_mfma_f32_16x16x32_bf16(Ah[mi], buh, uacc[mi][ni], 0, 0, 0);
                    uacc[mi][ni] = __builtin_amdgcn_mfma_f32_16x16x32_bf16(Ah[mi], bul, uacc[mi][ni], 0, 0, 0);
                    uacc[mi][ni] = __builtin_amdgcn_mfma_f32_16x16x32_bf16(Al[mi], buh, uacc[mi][ni], 0, 0, 0);
                }
            }
            __builtin_amdgcn_sched_barrier(0);         // no sinking below
            __builtin_amdgcn_s_barrier();              // reads done -> oldest buf reusable

            coff = (coff == 2 * BUF) ? 0 : coff + BUF;
            soff = (soff == 2 * BUF) ? 0 : soff + BUF;
        }

        // epilogue: act = silu(gate+bg)*(up+bu), split to bf16 hi/lo
#pragma unroll
        for (int ni = 0; ni < 2; ++ni) {
            int gcol = j0 + wc * 32 + ni * 16 + lr;
            float bg = b1[gcol];
            float bu = b1[DE + gcol];
#pragma unroll
            for (int mi = 0; mi < 2; ++mi) {
#pragma unroll
                for (int r = 0; r < 4; ++r) {
                    int trow = wr * 32 + mi * 16 + lgrp * 4 + r;
                    if (base + trow < cnt) {
                        float g = gacc[mi][ni][r] + bg;
                        float u = uacc[mi][ni][r] + bu;
                        float a = (g / (1.0f + expf(-g))) * u;
                        size_t off = (size_t)toks[trow] * DDIM + gcol;
                        u16 h = f2bf(a);
                        acth[off] = h;
                        actl[off] = f2bf(a - bf2f(h));
                    }
                }
            }
        }
    }
}

__global__ __launch_bounds__(256) void k_phaseA_v3(const u16* __restrict__ xh,
                                                   const u16* __restrict__ xl,
                                                   const u16* __restrict__ w1h,
                                                   const u16* __restrict__ w1l,
                                                   const float* __restrict__ b1,
                                                   const int* __restrict__ counts,
                                                   const int* __restrict__ bucket,
                                                   u16* __restrict__ acth,
                                                   u16* __restrict__ actl) {
    __shared__ int toks[64];
    __shared__ __align__(16) u16 lds[3 * 6 * 2048];   // 72 KiB -> 2 blocks/CU
    int y = blockIdx.y;  // 30 = 2+4+8+16 j-tiles
    if (y < 2)
        phaseA_v3<128>(xh, xl, w1h, w1l, b1, bucket + 0 * NTOK, counts[0], y, acth, actl, toks, lds);
    else if (y < 6)
        phaseA_v3<256>(xh, xl, w1h, w1l, b1, bucket + 1 * NTOK, counts[1], y - 2, acth, actl, toks, lds);
    else if (y < 14)
        phaseA_v3<512>(xh, xl, w1h, w1l, b1, bucket + 2 * NTOK, counts[2], y - 6, acth, actl, toks, lds);
    else
        phaseA_v3<1024>(xh, xl, w1h, w1l, b1, bucket + 3 * NTOK, counts[3], y - 14, acth, actl, toks, lds);
}

// ---------------- phase B: out = act @ w2[:, :DE]^T + b2; zero cols >= DE ----------------
// Same 3-buffer pipeline; Q=4 loads/wave/buffer; buffer stride 8192 u16 (16 KB).
template <int DE>
__device__ void phaseB_v3(const u16* __restrict__ acth, const u16* __restrict__ actl,
                          const u16* __restrict__ w2h, const u16* __restrict__ w2l,
                          const float* __restrict__ b2,
                          const int* __restrict__ bucket, int cnt, int it,
                          float* __restrict__ out,
                          int* toks, u16* lds) {
    const int tid = threadIdx.x;
    const int lane = tid & 63;
    const int wid = tid >> 6;
    const int wr = wid >> 1, wc = wid & 1;
    const int i0 = it * 64;
    const int lr = lane & 15;
    const int lgrp = lane >> 4;
    const int nk = DE / 32;
    constexpr int BUF = 8192;

    for (int tile = blockIdx.x; tile * 64 < cnt; tile += gridDim.x) {
        const int base = tile * 64;
        __syncthreads();
        if (tid < 64) {
            int p = base + tid;
            toks[tid] = bucket[p < cnt ? p : cnt - 1];
        }
        __syncthreads();

        const u16* src[4];
        int dstoff[4];
        {
            const int r16 = lane >> 2, pc = lane & 3;
#pragma unroll
            for (int q = 0; q < 4; ++q) {
                int idx = wid * 4 + q;
                int a = idx >> 2, p = idx & 3;
                int r = p * 16 + r16;
                int ko = (pc ^ ((r >> 1) & 3)) * 8;
                const u16* s;
                if (a == 0)      s = &acth[(size_t)toks[r] * DDIM + ko];
                else if (a == 1) s = &actl[(size_t)toks[r] * DDIM + ko];
                else if (a == 2) s = &w2h[(size_t)(i0 + r) * HDIM + ko];
                else             s = &w2l[(size_t)(i0 + r) * HDIM + ko];
                src[q] = s;
                dstoff[q] = a * 2048 + p * 512;
            }
        }

        f32x4 acc[2][2];
        const f32x4 zz = {0.f, 0.f, 0.f, 0.f};
#pragma unroll
        for (int mi = 0; mi < 2; ++mi)
#pragma unroll
            for (int ni = 0; ni < 2; ++ni) acc[mi][ni] = zz;

#pragma unroll
        for (int q = 0; q < 4; ++q) gload16(src[q], lds + dstoff[q]);
#pragma unroll
        for (int q = 0; q < 4; ++q) gload16(src[q] + 32, lds + BUF + dstoff[q]);

        int coff = 0;
        int soff = 2 * BUF;
        for (int kt = 0; kt < nk; ++kt) {
            if (kt + 2 < nk) {
                const int kc = (kt + 2) * 32;
#pragma unroll
                for (int q = 0; q < 4; ++q) gload16(src[q] + kc, lds + soff + dstoff[q]);
                asm volatile("s_waitcnt vmcnt(8)" ::: "memory");
            } else if (kt + 1 < nk) {
                asm volatile("s_waitcnt vmcnt(4)" ::: "memory");
            } else {
                asm volatile("s_waitcnt vmcnt(0)" ::: "memory");
            }
            __builtin_amdgcn_s_barrier();
            __builtin_amdgcn_sched_barrier(0);

            const u16* B = lds + coff;
            short8 Ah[2], Al[2];
#pragma unroll
            for (int mi = 0; mi < 2; ++mi) {
                int row = wr * 32 + mi * 16 + lr;
                int pb = (lgrp ^ ((row >> 1) & 3)) * 8;
                Ah[mi] = *(const short8*)&B[0 * 2048 + row * 32 + pb];
                Al[mi] = *(const short8*)&B[1 * 2048 + row * 32 + pb];
            }
#pragma unroll
            for (int ni = 0; ni < 2; ++ni) {
                int rowb = wc * 32 + ni * 16 + lr;
                int pb = (lgrp ^ ((rowb >> 1) & 3)) * 8;
                short8 bh = *(const short8*)&B[2 * 2048 + rowb * 32 + pb];
                short8 bl = *(const short8*)&B[3 * 2048 + rowb * 32 + pb];
#pragma unroll
                for (int mi = 0; mi < 2; ++mi) {
                    acc[mi][ni] = __builtin_amdgcn_mfma_f32_16x16x32_bf16(Ah[mi], bh, acc[mi][ni], 0, 0, 0);
                    acc[mi][ni] = __builtin_amdgcn_mfma_f32_16x16x32_bf16(Ah[mi], bl, acc[mi][ni], 0, 0, 0);
                    acc[mi][ni] = __builtin_amdgcn_mfma_f32_16x16x32_bf16(Al[mi], bh, acc[mi][ni], 0, 0, 0);
                }
            }
            __builtin_amdgcn_sched_barrier(0);
            __builtin_amdgcn_s_barrier();

            coff = (coff == 2 * BUF) ? 0 : coff + BUF;
            soff = (soff == 2 * BUF) ? 0 : soff + BUF;
        }

#pragma unroll
        for (int ni = 0; ni < 2; ++ni) {
            int icol = i0 + wc * 32 + ni * 16 + lr;
            float bb = b2[icol];
#pragma unroll
            for (int mi = 0; mi < 2; ++mi) {
#pragma unroll
                for (int r = 0; r < 4; ++r) {
                    int trow = wr * 32 + mi * 16 + lgrp * 4 + r;
                    if (base + trow < cnt)
                        out[(size_t)toks[trow] * DDIM + icol] = acc[mi][ni][r] + bb;
                }
            }
        }

        if (it == 0 && DE < DDIM) {            // zero-fill cols [DE, DDIM)
            constexpr int TAIL4 = (DDIM - DE) / 4;
            const float4 z{0.f, 0.f, 0.f, 0.f};
            for (int idx = tid; idx < 64 * TAIL4; idx += 256) {
                int r = idx / TAIL4, c = idx % TAIL4;
                if (base + r < cnt)
                    *(float4*)&out[(size_t)toks[r] * DDIM + DE + c * 4] = z;
            }
        }
    }
}

__global__ __launch_bounds__(256) void k_phaseB_v3(const u16* __restrict__ acth,
                                                   const u16* __restrict__ actl,
                                                   const u16* __restrict__ w2h,
                                                   const u16* __restrict__ w2l,
                                                   const float* __restrict__ b2,
                                                   const int* __restrict__ counts,
                                                   const int* __restrict__ bucket,
                                                   float* __restrict__ out) {
    __shared__ int toks[64];
    __shared__ __align__(16) u16 lds[3 * 4 * 2048];   // 48 KiB -> 3 blocks/CU
    int y = blockIdx.y;  // 30 = 2+4+8+16 i-tiles
    if (y < 2)
        phaseB_v3<128>(acth, actl, w2h, w2l, b2, bucket + 0 * NTOK, counts[0], y, out, toks, lds);
    else if (y < 6)
        phaseB_v3<256>(acth, actl, w2h, w2l, b2, bucket + 1 * NTOK, counts[1], y - 2, out, toks, lds);
    else if (y < 14)
        phaseB_v3<512>(acth, actl, w2h, w2l, b2, bucket + 2 * NTOK, counts[2], y - 6, out, toks, lds);
    else
        phaseB_v3<1024>(acth, actl, w2h, w2l, b2, bucket + 3 * NTOK, counts[3], y - 14, out, toks, lds);
}

// ==================================== launch =============================================
extern "C" void kernel_launch(void* const* d_in, const int* in_sizes, int n_in,
                              void* d_out, int out_size, void* d_ws, size_t ws_size,
                              hipStream_t stream) {
    const float* x  = (const float*)d_in[0];
    const float* w1 = (const float*)d_in[1];
    const float* b1 = (const float*)d_in[2];
    const float* w2 = (const float*)d_in[3];
    const float* b2 = (const float*)d_in[4];
    const int* mask = (const int*)d_in[5];
    float* out = (float*)d_out;

    // ws: counts@0 | bucket@256 (256KiB) | acth@262400 (32MiB) | actl (32MiB)
    //     | w1h | w1l | w2h | w2l (4MiB each) => 84,148,480 B (proven available r3/r7)
    char* wsb = (char*)d_ws;
    int* counts = (int*)wsb;
    int* bucket = (int*)(wsb + 256);
    u16* acth = (u16*)(wsb + 262400);
    u16* actl = (u16*)(wsb + 33816832);
    u16* w1h = (u16*)(wsb + 67371264);
    u16* w1l = (u16*)(wsb + 71565568);
    u16* w2h = (u16*)(wsb + 75759872);
    u16* w2l = (u16*)(wsb + 79954176);

    hipLaunchKernelGGL(k_zero, dim3(1), dim3(64), 0, stream, counts);
    hipLaunchKernelGGL(k_bin, dim3(NTOK / 256), dim3(256), 0, stream, mask, counts, bucket);

    // x hi/lo lives in d_out (dead until phaseB overwrites it with the real output)
    u16* xh = (u16*)d_out;
    u16* xl = xh + (size_t)NTOK * DDIM;
    hipLaunchKernelGGL(k_wsplit, dim3(1024), dim3(256), 0, stream, w1, w2, w1h, w1l, w2h, w2l);
    hipLaunchKernelGGL(k_xsplit, dim3(8192), dim3(256), 0, stream, x, xh, xl);
    hipLaunchKernelGGL(k_phaseA_v3, dim3(64, 30), dim3(256), 0, stream,
                       xh, xl, w1h, w1l, b1, counts, bucket, acth, actl);
    hipLaunchKernelGGL(k_phaseB_v3, dim3(64, 30), dim3(256), 0, stream,
                       acth, actl, w2h, w2l, b2, counts, bucket, out);
}